// Round 6
// baseline (1531.787 us; speedup 1.0000x reference)
//
#include <hip/hip_runtime.h>
#include <hip/hip_bf16.h>
#include <stdint.h>

// Problem dims (fixed instance)
#define N_ROWS 6272      // B*H*W = 8*28*28, = 49*128 exactly
#define DIM    1024
#define M_ROWS 16384
#define KNN    9
#define BMS    128       // score tile M
#define BNS    128       // score tile N (= j-panel width)
#define NPANEL 128       // M_ROWS / BNS
#define PBLK   12        // blocks per panel
#define TOPC   6         // candidates kept per (row, panel, col-half)
#define NCAND  (NPANEL * 2 * TOPC)   // 1536 per row
#define TRR    16        // rerank count
#define KPAD   36        // Kbuf row stride (dwords): 16B-aligned, 4-bank stagger

typedef __attribute__((ext_vector_type(4))) float f32x4;
typedef __attribute__((ext_vector_type(8))) short short8;

__device__ __forceinline__ unsigned short f2bf(float f) {
  union { float f; unsigned int u; } v; v.f = f;
  unsigned int u = v.u;
  return (unsigned short)((u + 0x7FFFu + ((u >> 16) & 1u)) >> 16); // RNE
}

__device__ __forceinline__ void async16(const void* g, void* l) {
  __builtin_amdgcn_global_load_lds(
      (const __attribute__((address_space(1))) unsigned int*)g,
      (__attribute__((address_space(3))) unsigned int*)l, 16, 0, 0);
}

// order-preserving float->uint (ascending float -> ascending uint)
__device__ __forceinline__ unsigned f2ord(float f) {
  unsigned u = __float_as_uint(f);
  return u ^ (0x80000000u + (u >> 31) * 0x7FFFFFFFu);
}

// ---- x = NCHW -> [N, D] transpose, fp32 + bf16 copies ----
__global__ void k_prep_x(const float* __restrict__ feat,
                         float* __restrict__ xf, unsigned short* __restrict__ xb) {
  const int n = blockIdx.x;
  const int b = n / 784, hw = n % 784;
  const float* src = feat + (size_t)b * (1024 * 784) + hw;  // stride 784 over c
  float* xrow = xf + (size_t)n * DIM;
  unsigned short* brow = xb + (size_t)n * DIM;
  for (int c = threadIdx.x; c < DIM; c += 256) {
    float v = src[(size_t)c * 784];
    xrow[c] = v;
    brow[c] = f2bf(v);
  }
}

// ---- memory bank: bf16 copy + row squared norms ----
__global__ void k_prep_m(const float* __restrict__ mb,
                         unsigned short* __restrict__ mbb, float* __restrict__ mnorm) {
  const int j = blockIdx.x;
  const int t = threadIdx.x;
  const float* src = mb + (size_t)j * DIM;
  unsigned short* dst = mbb + (size_t)j * DIM;
  float s = 0.f;
  for (int c = t; c < DIM; c += 256) {
    float v = src[c];
    dst[c] = f2bf(v);
    s += v * v;
  }
  __shared__ float red[4];
#pragma unroll
  for (int o = 32; o >= 1; o >>= 1) s += __shfl_down(s, o);
  if ((t & 63) == 0) red[t >> 6] = s;
  __syncthreads();
  if (t == 0) mnorm[j] = red[0] + red[1] + red[2] + red[3];
}

// ---- bf16 MFMA distance GEMM, 128x128 tiles, m97-shape (3-4 blocks/CU TLP) ----
// 1536 blocks: xcd = bx&7 (dispatch round-robin), 16 panels/XCD (4 MB B in L2),
// 12 blocks/panel sweep 49 row-tiles. Single-buffer BK=64, 2 barriers/K-step.
// Epilogue: keys -> padded Kbuf, float4 scan, sorted top-6 per (row, col-half).
__launch_bounds__(256, 3)
__global__ void k_score(const unsigned short* __restrict__ xb,
                        const unsigned short* __restrict__ mbb,
                        const float* __restrict__ mnorm,
                        unsigned int* __restrict__ cand) {
  __shared__ unsigned short S[2 * 8192];    // A 16 KB | B 16 KB
  __shared__ float mns[BNS];
  float* Kbuf = (float*)S;                  // 128*36*4 = 18.4 KB alias (post-K)

  const int bx = blockIdx.x;
  const int xcd = bx & 7, i = bx >> 3;      // i in [0,192)
  const int jbl = i & 15, u = i >> 4;       // 16 panels/XCD, u in [0,12)
  const int jb = xcd * 16 + jbl;            // [0,128)
  const int j0 = jb * BNS;
  const int rcount = (u == 0) ? 5 : 4;

  const int t = threadIdx.x;
  const int lane = t & 63, w = t >> 6;
  const int wr = w >> 1, wc = w & 1;        // wave grid 2 x 2
  const int l15 = lane & 15, lg = lane >> 4;
  const int srow = t >> 1, sub = t & 1;     // epilogue row / col-half

  // staging: 4 x 16B chunks per thread per operand; linear LDS dest,
  // XOR-swizzled SOURCE col (matched by swizzled fragment reads)
  int offL[4], srcOff[4];
  const unsigned short* bPtr[4];
#pragma unroll
  for (int cpy = 0; cpy < 4; ++cpy) {
    const int off = cpy * 2048 + t * 8;     // shorts
    const int row = off >> 6;
    const int col = (off & 63) ^ ((row & 7) << 3);
    offL[cpy] = off;
    srcOff[cpy] = row * DIM + col;
    bPtr[cpy] = mbb + (size_t)(j0 + row) * DIM + col;
  }
  if (t < BNS) mns[t] = mnorm[j0 + t];

#pragma unroll 1
  for (int ri = 0; ri < rcount; ++ri) {
    const int tile = (ri < 4) ? (u + 12 * ri) : 48;
    const int r0 = tile * BMS;
    const unsigned short* aBase = xb + (size_t)r0 * DIM;

    f32x4 acc[4][4];
#pragma unroll
    for (int mi = 0; mi < 4; ++mi)
#pragma unroll
      for (int ni = 0; ni < 4; ++ni) acc[mi][ni] = (f32x4){0.f, 0.f, 0.f, 0.f};

#pragma unroll 1
    for (int ks = 0; ks < 16; ++ks) {
      __syncthreads();                      // prev readers of S / Kbuf done
      const int kk = ks * 64;
#pragma unroll
      for (int cpy = 0; cpy < 4; ++cpy) {
        async16(aBase + srcOff[cpy] + kk, S + offL[cpy]);
        async16(bPtr[cpy] + kk, S + 8192 + offL[cpy]);
      }
      __syncthreads();                      // drains vmcnt; tile resident
      __builtin_amdgcn_s_setprio(1);
#pragma unroll
      for (int k2 = 0; k2 < 2; ++k2) {
        const int slot = (k2 * 32 + lg * 8) ^ ((l15 & 7) << 3);
        short8 af[4], bf[4];
#pragma unroll
        for (int mi = 0; mi < 4; ++mi)
          af[mi] = *(const short8*)(S + (wr * 64 + mi * 16 + l15) * 64 + slot);
#pragma unroll
        for (int ni = 0; ni < 4; ++ni)
          bf[ni] = *(const short8*)(S + 8192 + (wc * 64 + ni * 16 + l15) * 64 + slot);
#pragma unroll
        for (int mi = 0; mi < 4; ++mi)
#pragma unroll
          for (int ni = 0; ni < 4; ++ni)
            acc[mi][ni] = __builtin_amdgcn_mfma_f32_16x16x32_bf16(af[mi], bf[ni], acc[mi][ni], 0, 0, 0);
      }
      __builtin_amdgcn_s_setprio(0);
    }
    __syncthreads();                        // last MFMA reads done before Kbuf writes

    // ---- epilogue: 4 stages of 32 cols; sorted-desc top-6 per (row, half) ----
    unsigned tk[TOPC];
#pragma unroll
    for (int s = 0; s < TOPC; ++s) tk[s] = 0xFFFFFFFFu;

#pragma unroll 1
    for (int st = 0; st < 4; ++st) {
      if (wc == (st >> 1)) {                // 2 waves write 128 rows x 32 cols
        const int np = (st & 1) * 2;
#pragma unroll
        for (int mi = 0; mi < 4; ++mi) {
#pragma unroll
          for (int nq = 0; nq < 2; ++nq) {
            const int ni = np + nq;
            const int colL = nq * 16 + l15;
            const float mn = mns[st * 32 + colL];
#pragma unroll
            for (int e = 0; e < 4; ++e) {
              const int row = wr * 64 + mi * 16 + lg * 4 + e;
              Kbuf[row * KPAD + colL] = mn - 2.0f * acc[mi][ni][e];
            }
          }
        }
      }
      __syncthreads();
      const int cbase = st * 32 + sub * 16;
      const int jbase = j0 + cbase;
#pragma unroll
      for (int q = 0; q < 4; ++q) {
        const f32x4 v = *(const f32x4*)(Kbuf + srow * KPAD + sub * 16 + q * 4);
#pragma unroll
        for (int e = 0; e < 4; ++e) {
          const unsigned p = (f2ord(v[e]) & 0xFFFFC000u) | (unsigned)(jbase + q * 4 + e);
          if (p < tk[0]) {                  // replace max, bubble down (sorted desc)
            tk[0] = p;
#pragma unroll
            for (int s = 0; s < TOPC - 1; ++s) {
              const unsigned hi = tk[s] > tk[s + 1] ? tk[s] : tk[s + 1];
              const unsigned lo = tk[s] > tk[s + 1] ? tk[s + 1] : tk[s];
              tk[s] = hi; tk[s + 1] = lo;
            }
          }
        }
      }
      __syncthreads();                      // scan done before Kbuf reuse
    }
    {
      const size_t base = (size_t)(r0 + srow) * NCAND + (size_t)(jb * 2 + sub) * TOPC;
#pragma unroll
      for (int s = 0; s < TOPC; ++s) cand[base + s] = tk[s];
    }
  }
}

// ---- merge 1536 packed candidates -> exact-by-key top-16 -> fp64 rerank -> top-9 ----
__global__ void k_rerank(const float* __restrict__ xf, const float* __restrict__ mb,
                         const unsigned int* __restrict__ cand,
                         int* __restrict__ idx9, double* __restrict__ dsv) {
  const int n = blockIdx.x, t = threadIdx.x;
  __shared__ float    xs[DIM];
  __shared__ unsigned cs[NCAND];
  __shared__ unsigned sel[TRR];
  __shared__ double dpart[256];
  __shared__ double d2s[TRR];
  __shared__ double dist_s[TRR];
  __shared__ int    rank_s[TRR];

  const float* xrow = xf + (size_t)n * DIM;
  for (int c = t; c < DIM; c += 256) xs[c] = xrow[c];
  const size_t cb = (size_t)n * NCAND;
  for (int s = t; s < NCAND; s += 256) cs[s] = cand[cb + s];
  __syncthreads();

  if (t < 64) {  // wave 0: 64 lanes x 24 items, 16 extract-min rounds
    unsigned ck[24];
#pragma unroll
    for (int s = 0; s < 24; ++s) ck[s] = cs[t + 64 * s];
    for (int it = 0; it < TRR; ++it) {
      unsigned best = ck[0];
#pragma unroll
      for (int s = 1; s < 24; ++s) best = best < ck[s] ? best : ck[s];
#pragma unroll
      for (int off = 32; off >= 1; off >>= 1) {
        const unsigned o = (unsigned)__shfl_xor((int)best, off);
        best = best < o ? best : o;
      }
      if (t == 0) sel[it] = best;
#pragma unroll
      for (int s = 0; s < 24; ++s) if (ck[s] == best) ck[s] = 0xFFFFFFFFu;
    }
  }
  __syncthreads();
  {
    const int s = t >> 4, l16 = t & 15;
    const int j = (int)(sel[s] & 16383u);
    const float* mrow = mb + (size_t)j * DIM;
    double a = 0.0;
    for (int i = 0; i < 64; ++i) {
      const int c = l16 + (i << 4);
      const double d = (double)xs[c] - (double)mrow[c];
      a += d * d;
    }
    dpart[t] = a;
  }
  __syncthreads();
  if (t < TRR) {
    double v = 0.0;
    for (int i = 0; i < 16; ++i) v += dpart[t * 16 + i];
    d2s[t] = v;
    dist_s[t] = sqrt(v < 1e-12 ? 1e-12 : v);
  }
  __syncthreads();
  if (t < TRR) {
    const double v = d2s[t]; const int id = (int)(sel[t] & 16383u);
    int r = 0;
    for (int u = 0; u < TRR; ++u) {
      const double vu = d2s[u];
      const int idu = (int)(sel[u] & 16383u);
      if (vu < v || (vu == v && idu < id)) ++r;
    }
    rank_s[t] = r;
    if (r < KNN) idx9[n * KNN + r] = id;
  }
  __syncthreads();
  if (t == 0) {
    double sum = 0.0;
    for (int u = 0; u < TRR; ++u) if (rank_s[u] < KNN) sum += dist_s[u];
    dsv[n] = sum * (1.0 / KNN);
  }
}

// ---- global mean/std of per-row mean distance ----
__global__ void k_dsstats(const double* __restrict__ dsv, double* __restrict__ stats) {
  __shared__ double red[1024];
  const int t = threadIdx.x;
  double s = 0.0;
  for (int i = t; i < N_ROWS; i += 1024) s += dsv[i];
  red[t] = s; __syncthreads();
  for (int o = 512; o >= 1; o >>= 1) { if (t < o) red[t] += red[t + o]; __syncthreads(); }
  const double mean = red[0] / (double)N_ROWS;
  __syncthreads();
  double v = 0.0;
  for (int i = t; i < N_ROWS; i += 1024) { const double d = dsv[i] - mean; v += d * d; }
  red[t] = v; __syncthreads();
  for (int o = 512; o >= 1; o >>= 1) { if (t < o) red[t] += red[t + o]; __syncthreads(); }
  if (t == 0) {
    const double fullstd = sqrt(red[0] * (double)DIM / ((double)N_ROWS * DIM - 1.0));
    stats[0] = mean;
    stats[1] = fullstd + 1e-8;
  }
}

// ---- influence, row-norm, sigmoid noise, noised output + maps ----
__global__ void k_final(const float* __restrict__ xf, const float* __restrict__ mb,
                        const float* __restrict__ iw, const float* __restrict__ dwp,
                        const float* __restrict__ eps, const int* __restrict__ idx9,
                        const double* __restrict__ dsv, const double* __restrict__ stats,
                        float* __restrict__ out) {
  const int n = blockIdx.x, t = threadIdx.x;
  __shared__ float xs[DIM];
  __shared__ int js[KNN];
  __shared__ float rs1[4], rs2[4];
  const float* xrow = xf + (size_t)n * DIM;
  for (int c = t; c < DIM; c += 256) xs[c] = xrow[c];
  if (t < KNN) js[t] = idx9[n * KNN + t];
  __syncthreads();

  float infl[4];
  float s1 = 0.f, s2 = 0.f;
#pragma unroll
  for (int q = 0; q < 4; ++q) {
    const int c = t + q * 256;
    const float x = xs[c];
    float a = 0.f;
#pragma unroll
    for (int k = 0; k < KNN; ++k) a += fabsf(x - mb[(size_t)js[k] * DIM + c]);
    const float v = a * (1.0f / KNN) * iw[c];
    infl[q] = v; s1 += v; s2 += v * v;
  }
#pragma unroll
  for (int o = 32; o >= 1; o >>= 1) { s1 += __shfl_down(s1, o); s2 += __shfl_down(s2, o); }
  if ((t & 63) == 0) { rs1[t >> 6] = s1; rs2[t >> 6] = s2; }
  __syncthreads();
  const float sum = rs1[0] + rs1[1] + rs1[2] + rs1[3];
  const float sq  = rs2[0] + rs2[1] + rs2[2] + rs2[3];
  const float mean = sum * (1.0f / DIM);
  float var = (sq - (float)DIM * mean * mean) * (1.0f / (DIM - 1));
  var = fmaxf(var, 0.f);
  const float inv = 1.0f / (sqrtf(var) + 1e-8f);
  const float dn = (float)(((double)dsv[n] - stats[0]) / stats[1]);
  const float zb = dwp[0] * dn;

  const int b = n / 784, hw = n % 784;
  float* op = out + (size_t)b * (1024 * 784) + hw;
  const float* ep = eps + (size_t)n * DIM;
  float si = 0.f, sn = 0.f;
#pragma unroll
  for (int q = 0; q < 4; ++q) {
    const int c = t + q * 256;
    const float v = infl[q];
    const float z = (v - mean) * inv + zb;
    const float ns = 0.01f + 0.49f / (1.0f + expf(-z));
    op[(size_t)c * 784] = xs[c] + ep[c] * ns;
    si += v; sn += ns;
  }
  __syncthreads();  // rs1/rs2 reads above complete before reuse
#pragma unroll
  for (int o = 32; o >= 1; o >>= 1) { si += __shfl_down(si, o); sn += __shfl_down(sn, o); }
  if ((t & 63) == 0) { rs1[t >> 6] = si; rs2[t >> 6] = sn; }
  __syncthreads();
  if (t == 0) {
    out[6422528 + n]        = (rs1[0] + rs1[1] + rs1[2] + rs1[3]) * (1.0f / DIM);
    out[6422528 + 6272 + n] = (rs2[0] + rs2[1] + rs2[2] + rs2[3]) * (1.0f / DIM);
  }
}

extern "C" void kernel_launch(void* const* d_in, const int* in_sizes, int n_in,
                              void* d_out, int out_size, void* d_ws, size_t ws_size,
                              hipStream_t stream) {
  (void)in_sizes; (void)n_in; (void)out_size; (void)ws_size;
  const float* feat = (const float*)d_in[0];
  const float* mb   = (const float*)d_in[1];
  const float* iw   = (const float*)d_in[2];
  const float* dw   = (const float*)d_in[3];
  const float* eps  = (const float*)d_in[4];
  float* out = (float*)d_out;

  char* p = (char*)d_ws;
  float* xf = (float*)p;                     p += (size_t)N_ROWS * DIM * 4;
  unsigned short* xbf = (unsigned short*)p;  p += (size_t)N_ROWS * DIM * 2;
  unsigned short* mbb = (unsigned short*)p;  p += (size_t)M_ROWS * DIM * 2;
  float* mnorm = (float*)p;                  p += (size_t)M_ROWS * 4;
  unsigned int* cand = (unsigned int*)p;     p += (size_t)N_ROWS * NCAND * 4;
  int* idx9 = (int*)p;                       p += (size_t)N_ROWS * KNN * 4;
  p = (char*)(((uintptr_t)p + 255) & ~(uintptr_t)255);
  double* dsv = (double*)p;                  p += (size_t)N_ROWS * 8;
  double* stats = (double*)p;                p += 64;
  // total ~110 MB of d_ws

  k_prep_x<<<N_ROWS, 256, 0, stream>>>(feat, xf, xbf);
  k_prep_m<<<M_ROWS, 256, 0, stream>>>(mb, mbb, mnorm);
  k_score<<<NPANEL * PBLK, 256, 0, stream>>>(xbf, mbb, mnorm, cand);
  k_rerank<<<N_ROWS, 256, 0, stream>>>(xf, mb, cand, idx9, dsv);
  k_dsstats<<<1, 1024, 0, stream>>>(dsv, stats);
  k_final<<<N_ROWS, 256, 0, stream>>>(xf, mb, iw, dw, eps, idx9, dsv, stats, out);
}

// Round 7
// 661.989 us; speedup vs baseline: 2.3139x; 2.3139x over previous
//
#include <hip/hip_runtime.h>
#include <hip/hip_bf16.h>
#include <stdint.h>

// Problem dims (fixed instance)
#define N_ROWS 6272      // B*H*W = 8*28*28, = 49*128 exactly
#define DIM    1024
#define M_ROWS 16384
#define KNN    9
#define BMS    128       // score tile M
#define BNS    128       // score tile N (= j-panel width)
#define NPANEL 128       // M_ROWS / BNS (global panel count)
#define TOPC   6         // candidates kept per (row, panel, col-half)
#define NCAND  (NPANEL * 2 * TOPC)   // 1536 per row
#define TRR    16        // rerank count
#define KPAD   36        // Kbuf row stride (dwords): 16B-aligned, 4-bank stagger

typedef __attribute__((ext_vector_type(4))) float f32x4;
typedef __attribute__((ext_vector_type(8))) short short8;

__device__ __forceinline__ unsigned short f2bf(float f) {
  union { float f; unsigned int u; } v; v.f = f;
  unsigned int u = v.u;
  return (unsigned short)((u + 0x7FFFu + ((u >> 16) & 1u)) >> 16); // RNE
}

__device__ __forceinline__ void async16(const void* g, void* l) {
  __builtin_amdgcn_global_load_lds(
      (const __attribute__((address_space(1))) unsigned int*)g,
      (__attribute__((address_space(3))) unsigned int*)l, 16, 0, 0);
}

// order-preserving float->uint (ascending float -> ascending uint)
__device__ __forceinline__ unsigned f2ord(float f) {
  unsigned u = __float_as_uint(f);
  return u ^ (0x80000000u + (u >> 31) * 0x7FFFFFFFu);
}

// ---- x = NCHW -> [N, D] transpose, fp32 + bf16 copies ----
__global__ void k_prep_x(const float* __restrict__ feat,
                         float* __restrict__ xf, unsigned short* __restrict__ xb) {
  const int n = blockIdx.x;
  const int b = n / 784, hw = n % 784;
  const float* src = feat + (size_t)b * (1024 * 784) + hw;  // stride 784 over c
  float* xrow = xf + (size_t)n * DIM;
  unsigned short* brow = xb + (size_t)n * DIM;
  for (int c = threadIdx.x; c < DIM; c += 256) {
    float v = src[(size_t)c * 784];
    xrow[c] = v;
    brow[c] = f2bf(v);
  }
}

// ---- memory bank: bf16 copy + row squared norms ----
__global__ void k_prep_m(const float* __restrict__ mb,
                         unsigned short* __restrict__ mbb, float* __restrict__ mnorm) {
  const int j = blockIdx.x;
  const int t = threadIdx.x;
  const float* src = mb + (size_t)j * DIM;
  unsigned short* dst = mbb + (size_t)j * DIM;
  float s = 0.f;
  for (int c = t; c < DIM; c += 256) {
    float v = src[c];
    dst[c] = f2bf(v);
    s += v * v;
  }
  __shared__ float red[4];
#pragma unroll
  for (int o = 32; o >= 1; o >>= 1) s += __shfl_down(s, o);
  if ((t & 63) == 0) red[t >> 6] = s;
  __syncthreads();
  if (t == 0) mnorm[j] = red[0] + red[1] + red[2] + red[3];
}

// ---- bf16 MFMA distance GEMM, 128x128 tiles, L2-budgeted schedule ----
// Two serialized launches (jhalf=0,1). Per launch: 512 blocks (2/CU by 64.5 KB
// LDS, all co-resident). XCD x owns B rows [jhalf*8192 + x*1024, +1024) = 2 MB
// (8 panels of 128). 8 A-groups/XCD sweep A-tiles stride-8 => 8 distinct
// consecutive A-tiles concurrent = 2 MB. Total 4 MB = L2 (no victim thrash).
// Block: 256 thr / 4 waves (2x2), double-buffered BK=64, counted vmcnt.
__launch_bounds__(256, 2)
__global__ void k_score(const unsigned short* __restrict__ xb,
                        const unsigned short* __restrict__ mbb,
                        const float* __restrict__ mnorm,
                        unsigned int* __restrict__ cand, int jhalf) {
  __shared__ unsigned short S[4 * 8192];    // A0|A1|B0|B1, 16 KB each = 64 KB
  __shared__ float mns[BNS];
  float* Kbuf = (float*)S;                  // 128*36*4 = 18.4 KB alias (post-K)

  const int bx = blockIdx.x;
  const int xcd = bx & 7, i = bx >> 3;      // dispatch round-robins XCDs
  const int panel = i & 7, agroup = i >> 3; // 8 panels x 8 A-groups per XCD
  const int j0 = jhalf * 8192 + xcd * 1024 + panel * BNS;
  const int pglob = jhalf * 64 + xcd * 8 + panel;   // [0,128)

  const int t = threadIdx.x;
  const int lane = t & 63, w = t >> 6;
  const int wr = w >> 1, wc = w & 1;        // wave grid 2 x 2
  const int l15 = lane & 15, lg = lane >> 4;
  const int srow = t >> 1, sub = t & 1;     // epilogue row / col-half

  // staging: 4 x 16B chunks per thread per operand per K-step; linear LDS dest,
  // XOR-swizzled SOURCE col (matched by swizzled fragment reads)
  int offL[4], srcOff[4];
  const unsigned short* bPtr[4];
#pragma unroll
  for (int cpy = 0; cpy < 4; ++cpy) {
    const int off = cpy * 2048 + t * 8;     // shorts within one 16 KB buf
    const int row = off >> 6;
    const int col = (off & 63) ^ ((row & 7) << 3);
    offL[cpy] = off;
    srcOff[cpy] = row * DIM + col;
    bPtr[cpy] = mbb + (size_t)(j0 + row) * DIM + col;
  }
  if (t < BNS) mns[t] = mnorm[j0 + t];

#pragma unroll 1
  for (int k7 = 0; k7 < 7; ++k7) {
    const int tile = agroup + 8 * k7;       // stride-8 sweep keeps groups aligned
    if (tile >= 49) break;
    const int r0 = tile * BMS;
    const unsigned short* aBase = xb + (size_t)r0 * DIM;

    f32x4 acc[4][4];
#pragma unroll
    for (int mi = 0; mi < 4; ++mi)
#pragma unroll
      for (int ni = 0; ni < 4; ++ni) acc[mi][ni] = (f32x4){0.f, 0.f, 0.f, 0.f};

    // prologue: stage K-step 0 into buf0 (epilogue barrier preceded us)
#pragma unroll
    for (int cpy = 0; cpy < 4; ++cpy) {
      async16(aBase + srcOff[cpy], S + offL[cpy]);
      async16(bPtr[cpy], S + 16384 + offL[cpy]);
    }
#pragma unroll 1
    for (int ks = 0; ks < 16; ++ks) {
      if (ks < 15) {                        // stage next K-step into other buf
        const int kk = (ks + 1) * 64;
        const int nb = ((ks + 1) & 1) * 8192;
#pragma unroll
        for (int cpy = 0; cpy < 4; ++cpy) {
          async16(aBase + srcOff[cpy] + kk, S + nb + offL[cpy]);
          async16(bPtr[cpy] + kk, S + 16384 + nb + offL[cpy]);
        }
        asm volatile("s_waitcnt vmcnt(8)" ::: "memory");  // tile ks done; ks+1 in flight
      } else {
        asm volatile("s_waitcnt vmcnt(0)" ::: "memory");
      }
      __builtin_amdgcn_s_barrier();         // tile ks resident for ALL waves
      const unsigned short* Ab = S + (ks & 1) * 8192;
      const unsigned short* Bb = S + 16384 + (ks & 1) * 8192;
      __builtin_amdgcn_s_setprio(1);
#pragma unroll
      for (int k2 = 0; k2 < 2; ++k2) {
        const int slot = (k2 * 32 + lg * 8) ^ ((l15 & 7) << 3);
        short8 af[4], bf[4];
#pragma unroll
        for (int mi = 0; mi < 4; ++mi)
          af[mi] = *(const short8*)(Ab + (wr * 64 + mi * 16 + l15) * 64 + slot);
#pragma unroll
        for (int ni = 0; ni < 4; ++ni)
          bf[ni] = *(const short8*)(Bb + (wc * 64 + ni * 16 + l15) * 64 + slot);
#pragma unroll
        for (int mi = 0; mi < 4; ++mi)
#pragma unroll
          for (int ni = 0; ni < 4; ++ni)
            acc[mi][ni] = __builtin_amdgcn_mfma_f32_16x16x32_bf16(af[mi], bf[ni], acc[mi][ni], 0, 0, 0);
      }
      __builtin_amdgcn_s_setprio(0);
      asm volatile("" ::: "memory");
      __builtin_amdgcn_s_barrier();         // all reads of buf[ks&1] done
    }

    // ---- epilogue: 4 stages of 32 cols; sorted-desc top-6 per (row, half) ----
    unsigned tk[TOPC];
#pragma unroll
    for (int s = 0; s < TOPC; ++s) tk[s] = 0xFFFFFFFFu;

#pragma unroll 1
    for (int st = 0; st < 4; ++st) {
      if (wc == (st >> 1)) {                // 2 waves write 128 rows x 32 cols
        const int np = (st & 1) * 2;
#pragma unroll
        for (int mi = 0; mi < 4; ++mi) {
#pragma unroll
          for (int nq = 0; nq < 2; ++nq) {
            const int ni = np + nq;
            const int colL = nq * 16 + l15;
            const float mn = mns[st * 32 + colL];
#pragma unroll
            for (int e = 0; e < 4; ++e) {
              const int row = wr * 64 + mi * 16 + lg * 4 + e;
              Kbuf[row * KPAD + colL] = mn - 2.0f * acc[mi][ni][e];
            }
          }
        }
      }
      __syncthreads();
      const int jbase = j0 + st * 32 + sub * 16;
#pragma unroll
      for (int q = 0; q < 4; ++q) {
        const f32x4 v = *(const f32x4*)(Kbuf + srow * KPAD + sub * 16 + q * 4);
#pragma unroll
        for (int e = 0; e < 4; ++e) {
          const unsigned p = (f2ord(v[e]) & 0xFFFFC000u) | (unsigned)(jbase + q * 4 + e);
          if (p < tk[0]) {                  // replace max, bubble down (sorted desc)
            tk[0] = p;
#pragma unroll
            for (int s = 0; s < TOPC - 1; ++s) {
              const unsigned hi = tk[s] > tk[s + 1] ? tk[s] : tk[s + 1];
              const unsigned lo = tk[s] > tk[s + 1] ? tk[s + 1] : tk[s];
              tk[s] = hi; tk[s + 1] = lo;
            }
          }
        }
      }
      __syncthreads();                      // scan done before Kbuf/S reuse
    }
    {
      const size_t base = (size_t)(r0 + srow) * NCAND + (size_t)(pglob * 2 + sub) * TOPC;
#pragma unroll
      for (int s = 0; s < TOPC; ++s) cand[base + s] = tk[s];
    }
  }
}

// ---- merge 1536 packed candidates -> exact-by-key top-16 -> fp64 rerank -> top-9 ----
__global__ void k_rerank(const float* __restrict__ xf, const float* __restrict__ mb,
                         const unsigned int* __restrict__ cand,
                         int* __restrict__ idx9, double* __restrict__ dsv) {
  const int n = blockIdx.x, t = threadIdx.x;
  __shared__ float    xs[DIM];
  __shared__ unsigned cs[NCAND];
  __shared__ unsigned sel[TRR];
  __shared__ double dpart[256];
  __shared__ double d2s[TRR];
  __shared__ double dist_s[TRR];
  __shared__ int    rank_s[TRR];

  const float* xrow = xf + (size_t)n * DIM;
  for (int c = t; c < DIM; c += 256) xs[c] = xrow[c];
  const size_t cb = (size_t)n * NCAND;
  for (int s = t; s < NCAND; s += 256) cs[s] = cand[cb + s];
  __syncthreads();

  if (t < 64) {  // wave 0: 64 lanes x 24 items, 16 extract-min rounds
    unsigned ck[24];
#pragma unroll
    for (int s = 0; s < 24; ++s) ck[s] = cs[t + 64 * s];
    for (int it = 0; it < TRR; ++it) {
      unsigned best = ck[0];
#pragma unroll
      for (int s = 1; s < 24; ++s) best = best < ck[s] ? best : ck[s];
#pragma unroll
      for (int off = 32; off >= 1; off >>= 1) {
        const unsigned o = (unsigned)__shfl_xor((int)best, off);
        best = best < o ? best : o;
      }
      if (t == 0) sel[it] = best;
#pragma unroll
      for (int s = 0; s < 24; ++s) if (ck[s] == best) ck[s] = 0xFFFFFFFFu;
    }
  }
  __syncthreads();
  {
    const int s = t >> 4, l16 = t & 15;
    const int j = (int)(sel[s] & 16383u);
    const float* mrow = mb + (size_t)j * DIM;
    double a = 0.0;
    for (int i = 0; i < 64; ++i) {
      const int c = l16 + (i << 4);
      const double d = (double)xs[c] - (double)mrow[c];
      a += d * d;
    }
    dpart[t] = a;
  }
  __syncthreads();
  if (t < TRR) {
    double v = 0.0;
    for (int i = 0; i < 16; ++i) v += dpart[t * 16 + i];
    d2s[t] = v;
    dist_s[t] = sqrt(v < 1e-12 ? 1e-12 : v);
  }
  __syncthreads();
  if (t < TRR) {
    const double v = d2s[t]; const int id = (int)(sel[t] & 16383u);
    int r = 0;
    for (int u = 0; u < TRR; ++u) {
      const double vu = d2s[u];
      const int idu = (int)(sel[u] & 16383u);
      if (vu < v || (vu == v && idu < id)) ++r;
    }
    rank_s[t] = r;
    if (r < KNN) idx9[n * KNN + r] = id;
  }
  __syncthreads();
  if (t == 0) {
    double sum = 0.0;
    for (int u = 0; u < TRR; ++u) if (rank_s[u] < KNN) sum += dist_s[u];
    dsv[n] = sum * (1.0 / KNN);
  }
}

// ---- global mean/std of per-row mean distance ----
__global__ void k_dsstats(const double* __restrict__ dsv, double* __restrict__ stats) {
  __shared__ double red[1024];
  const int t = threadIdx.x;
  double s = 0.0;
  for (int i = t; i < N_ROWS; i += 1024) s += dsv[i];
  red[t] = s; __syncthreads();
  for (int o = 512; o >= 1; o >>= 1) { if (t < o) red[t] += red[t + o]; __syncthreads(); }
  const double mean = red[0] / (double)N_ROWS;
  __syncthreads();
  double v = 0.0;
  for (int i = t; i < N_ROWS; i += 1024) { const double d = dsv[i] - mean; v += d * d; }
  red[t] = v; __syncthreads();
  for (int o = 512; o >= 1; o >>= 1) { if (t < o) red[t] += red[t + o]; __syncthreads(); }
  if (t == 0) {
    const double fullstd = sqrt(red[0] * (double)DIM / ((double)N_ROWS * DIM - 1.0));
    stats[0] = mean;
    stats[1] = fullstd + 1e-8;
  }
}

// ---- influence, row-norm, sigmoid noise, noised output + maps ----
__global__ void k_final(const float* __restrict__ xf, const float* __restrict__ mb,
                        const float* __restrict__ iw, const float* __restrict__ dwp,
                        const float* __restrict__ eps, const int* __restrict__ idx9,
                        const double* __restrict__ dsv, const double* __restrict__ stats,
                        float* __restrict__ out) {
  const int n = blockIdx.x, t = threadIdx.x;
  __shared__ float xs[DIM];
  __shared__ int js[KNN];
  __shared__ float rs1[4], rs2[4];
  const float* xrow = xf + (size_t)n * DIM;
  for (int c = t; c < DIM; c += 256) xs[c] = xrow[c];
  if (t < KNN) js[t] = idx9[n * KNN + t];
  __syncthreads();

  float infl[4];
  float s1 = 0.f, s2 = 0.f;
#pragma unroll
  for (int q = 0; q < 4; ++q) {
    const int c = t + q * 256;
    const float x = xs[c];
    float a = 0.f;
#pragma unroll
    for (int k = 0; k < KNN; ++k) a += fabsf(x - mb[(size_t)js[k] * DIM + c]);
    const float v = a * (1.0f / KNN) * iw[c];
    infl[q] = v; s1 += v; s2 += v * v;
  }
#pragma unroll
  for (int o = 32; o >= 1; o >>= 1) { s1 += __shfl_down(s1, o); s2 += __shfl_down(s2, o); }
  if ((t & 63) == 0) { rs1[t >> 6] = s1; rs2[t >> 6] = s2; }
  __syncthreads();
  const float sum = rs1[0] + rs1[1] + rs1[2] + rs1[3];
  const float sq  = rs2[0] + rs2[1] + rs2[2] + rs2[3];
  const float mean = sum * (1.0f / DIM);
  float var = (sq - (float)DIM * mean * mean) * (1.0f / (DIM - 1));
  var = fmaxf(var, 0.f);
  const float inv = 1.0f / (sqrtf(var) + 1e-8f);
  const float dn = (float)(((double)dsv[n] - stats[0]) / stats[1]);
  const float zb = dwp[0] * dn;

  const int b = n / 784, hw = n % 784;
  float* op = out + (size_t)b * (1024 * 784) + hw;
  const float* ep = eps + (size_t)n * DIM;
  float si = 0.f, sn = 0.f;
#pragma unroll
  for (int q = 0; q < 4; ++q) {
    const int c = t + q * 256;
    const float v = infl[q];
    const float z = (v - mean) * inv + zb;
    const float ns = 0.01f + 0.49f / (1.0f + expf(-z));
    op[(size_t)c * 784] = xs[c] + ep[c] * ns;
    si += v; sn += ns;
  }
  __syncthreads();  // rs1/rs2 reads above complete before reuse
#pragma unroll
  for (int o = 32; o >= 1; o >>= 1) { si += __shfl_down(si, o); sn += __shfl_down(sn, o); }
  if ((t & 63) == 0) { rs1[t >> 6] = si; rs2[t >> 6] = sn; }
  __syncthreads();
  if (t == 0) {
    out[6422528 + n]        = (rs1[0] + rs1[1] + rs1[2] + rs1[3]) * (1.0f / DIM);
    out[6422528 + 6272 + n] = (rs2[0] + rs2[1] + rs2[2] + rs2[3]) * (1.0f / DIM);
  }
}

extern "C" void kernel_launch(void* const* d_in, const int* in_sizes, int n_in,
                              void* d_out, int out_size, void* d_ws, size_t ws_size,
                              hipStream_t stream) {
  (void)in_sizes; (void)n_in; (void)out_size; (void)ws_size;
  const float* feat = (const float*)d_in[0];
  const float* mb   = (const float*)d_in[1];
  const float* iw   = (const float*)d_in[2];
  const float* dw   = (const float*)d_in[3];
  const float* eps  = (const float*)d_in[4];
  float* out = (float*)d_out;

  char* p = (char*)d_ws;
  float* xf = (float*)p;                     p += (size_t)N_ROWS * DIM * 4;
  unsigned short* xbf = (unsigned short*)p;  p += (size_t)N_ROWS * DIM * 2;
  unsigned short* mbb = (unsigned short*)p;  p += (size_t)M_ROWS * DIM * 2;
  float* mnorm = (float*)p;                  p += (size_t)M_ROWS * 4;
  unsigned int* cand = (unsigned int*)p;     p += (size_t)N_ROWS * NCAND * 4;
  int* idx9 = (int*)p;                       p += (size_t)N_ROWS * KNN * 4;
  p = (char*)(((uintptr_t)p + 255) & ~(uintptr_t)255);
  double* dsv = (double*)p;                  p += (size_t)N_ROWS * 8;
  double* stats = (double*)p;                p += 64;
  // total ~110 MB of d_ws

  k_prep_x<<<N_ROWS, 256, 0, stream>>>(feat, xf, xbf);
  k_prep_m<<<M_ROWS, 256, 0, stream>>>(mb, mbb, mnorm);
  // Two serialized half-B launches keep per-XCD working set at 4 MB (= L2).
  k_score<<<512, 256, 0, stream>>>(xbf, mbb, mnorm, cand, 0);
  k_score<<<512, 256, 0, stream>>>(xbf, mbb, mnorm, cand, 1);
  k_rerank<<<N_ROWS, 256, 0, stream>>>(xf, mb, cand, idx9, dsv);
  k_dsstats<<<1, 1024, 0, stream>>>(dsv, stats);
  k_final<<<N_ROWS, 256, 0, stream>>>(xf, mb, iw, dw, eps, idx9, dsv, stats, out);
}

// Round 8
// 524.302 us; speedup vs baseline: 2.9216x; 1.2626x over previous
//
#include <hip/hip_runtime.h>
#include <hip/hip_bf16.h>
#include <stdint.h>

// Problem dims (fixed instance)
#define N_ROWS 6272      // B*H*W = 8*28*28, = 49*128 exactly
#define DIM    1024
#define M_ROWS 16384
#define KNN    9
#define BMS    128       // score tile M
#define BNS    128       // score tile N (= j-panel width)
#define NPANEL 128       // M_ROWS / BNS (global panel count)
#define TOPC   6         // candidates kept per (row, panel, col-half)
#define NCAND  (NPANEL * 2 * TOPC)   // 1536 per row
#define TRR    16        // rerank count

typedef __attribute__((ext_vector_type(4))) float f32x4;
typedef __attribute__((ext_vector_type(8))) short short8;

__device__ __forceinline__ unsigned short f2bf(float f) {
  union { float f; unsigned int u; } v; v.f = f;
  unsigned int u = v.u;
  return (unsigned short)((u + 0x7FFFu + ((u >> 16) & 1u)) >> 16); // RNE
}

__device__ __forceinline__ void async16(const void* g, void* l) {
  __builtin_amdgcn_global_load_lds(
      (const __attribute__((address_space(1))) unsigned int*)g,
      (__attribute__((address_space(3))) unsigned int*)l, 16, 0, 0);
}

// order-preserving float->uint (ascending float -> ascending uint)
__device__ __forceinline__ unsigned f2ord(float f) {
  unsigned u = __float_as_uint(f);
  return u ^ (0x80000000u + (u >> 31) * 0x7FFFFFFFu);
}

// Kbuf column swizzle: 16B-granular, bijective within a 128-col row
__device__ __forceinline__ int kswz(int row, int col) {
  return col ^ ((row & 7) << 2) ^ (((row >> 3) & 1) << 5);
}

// ---- x = NCHW -> [N, D] transpose, fp32 + bf16 copies ----
__global__ void k_prep_x(const float* __restrict__ feat,
                         float* __restrict__ xf, unsigned short* __restrict__ xb) {
  const int n = blockIdx.x;
  const int b = n / 784, hw = n % 784;
  const float* src = feat + (size_t)b * (1024 * 784) + hw;  // stride 784 over c
  float* xrow = xf + (size_t)n * DIM;
  unsigned short* brow = xb + (size_t)n * DIM;
  for (int c = threadIdx.x; c < DIM; c += 256) {
    float v = src[(size_t)c * 784];
    xrow[c] = v;
    brow[c] = f2bf(v);
  }
}

// ---- memory bank: bf16 copy + row squared norms ----
__global__ void k_prep_m(const float* __restrict__ mb,
                         unsigned short* __restrict__ mbb, float* __restrict__ mnorm) {
  const int j = blockIdx.x;
  const int t = threadIdx.x;
  const float* src = mb + (size_t)j * DIM;
  unsigned short* dst = mbb + (size_t)j * DIM;
  float s = 0.f;
  for (int c = t; c < DIM; c += 256) {
    float v = src[c];
    dst[c] = f2bf(v);
    s += v * v;
  }
  __shared__ float red[4];
#pragma unroll
  for (int o = 32; o >= 1; o >>= 1) s += __shfl_down(s, o);
  if ((t & 63) == 0) red[t >> 6] = s;
  __syncthreads();
  if (t == 0) mnorm[j] = red[0] + red[1] + red[2] + red[3];
}

// ---- bf16 MFMA distance GEMM, 128x128 tiles, L2-budgeted, balanced ----
// Two serialized launches (jhalf=0,1). Per launch: 448 blocks; XCD x owns B
// rows [jhalf*8192 + x*1024, +1024) = 2 MB (8 panels). 7 A-groups/XCD sweep
// tiles {g + 7*k} (7 each, perfectly balanced); concurrent A = 7 consecutive
// tiles = 1.75 MB. 2 MB B + 1.75 MB A < 4 MB L2 (slack vs drift).
// Block: 256 thr / 4 waves (2x2), double-buffered BK=64, counted vmcnt.
// Epilogue: single-stage all-wave key write into swizzled 64 KB Kbuf, one scan.
__launch_bounds__(256, 2)
__global__ void k_score(const unsigned short* __restrict__ xb,
                        const unsigned short* __restrict__ mbb,
                        const float* __restrict__ mnorm,
                        unsigned int* __restrict__ cand, int jhalf) {
  __shared__ unsigned short S[4 * 8192];    // A0|A1|B0|B1, 16 KB each = 64 KB
  __shared__ float mns[BNS];
  float* Kbuf = (float*)S;                  // 128x128 f32 = 64 KB alias (post-K)

  const int bx = blockIdx.x;
  const int xcd = bx & 7, i = bx >> 3;      // dispatch round-robins XCDs
  const int panel = i & 7, agroup = i >> 3; // 8 panels x 7 A-groups per XCD
  const int j0 = jhalf * 8192 + xcd * 1024 + panel * BNS;
  const int pglob = jhalf * 64 + xcd * 8 + panel;   // [0,128)

  const int t = threadIdx.x;
  const int lane = t & 63, w = t >> 6;
  const int wr = w >> 1, wc = w & 1;        // wave grid 2 x 2
  const int l15 = lane & 15, lg = lane >> 4;

  // staging: 4 x 16B chunks per thread per operand per K-step; linear LDS dest,
  // XOR-swizzled SOURCE col (matched by swizzled fragment reads)
  int offL[4], srcOff[4];
  const unsigned short* bPtr[4];
#pragma unroll
  for (int cpy = 0; cpy < 4; ++cpy) {
    const int off = cpy * 2048 + t * 8;     // shorts within one 16 KB buf
    const int row = off >> 6;
    const int col = (off & 63) ^ ((row & 7) << 3);
    offL[cpy] = off;
    srcOff[cpy] = row * DIM + col;
    bPtr[cpy] = mbb + (size_t)(j0 + row) * DIM + col;
  }
  if (t < BNS) mns[t] = mnorm[j0 + t];

#pragma unroll 1
  for (int k7 = 0; k7 < 7; ++k7) {
    const int tile = agroup + 7 * k7;       // 7 groups hold 7 consecutive tiles
    const int r0 = tile * BMS;
    const unsigned short* aBase = xb + (size_t)r0 * DIM;

    f32x4 acc[4][4];
#pragma unroll
    for (int mi = 0; mi < 4; ++mi)
#pragma unroll
      for (int ni = 0; ni < 4; ++ni) acc[mi][ni] = (f32x4){0.f, 0.f, 0.f, 0.f};

    // prologue: stage K-step 0 into buf0 (epilogue barrier preceded us)
#pragma unroll
    for (int cpy = 0; cpy < 4; ++cpy) {
      async16(aBase + srcOff[cpy], S + offL[cpy]);
      async16(bPtr[cpy], S + 16384 + offL[cpy]);
    }
#pragma unroll 1
    for (int ks = 0; ks < 16; ++ks) {
      if (ks < 15) {                        // stage next K-step into other buf
        const int kk = (ks + 1) * 64;
        const int nb = ((ks + 1) & 1) * 8192;
#pragma unroll
        for (int cpy = 0; cpy < 4; ++cpy) {
          async16(aBase + srcOff[cpy] + kk, S + nb + offL[cpy]);
          async16(bPtr[cpy] + kk, S + 16384 + nb + offL[cpy]);
        }
        asm volatile("s_waitcnt vmcnt(8)" ::: "memory");  // tile ks landed; ks+1 in flight
      } else {
        asm volatile("s_waitcnt vmcnt(0)" ::: "memory");
      }
      __builtin_amdgcn_s_barrier();         // tile ks resident for ALL waves
      const unsigned short* Ab = S + (ks & 1) * 8192;
      const unsigned short* Bb = S + 16384 + (ks & 1) * 8192;
#pragma unroll
      for (int k2 = 0; k2 < 2; ++k2) {
        const int slot = (k2 * 32 + lg * 8) ^ ((l15 & 7) << 3);
        short8 af[4], bf[4];
#pragma unroll
        for (int mi = 0; mi < 4; ++mi)
          af[mi] = *(const short8*)(Ab + (wr * 64 + mi * 16 + l15) * 64 + slot);
#pragma unroll
        for (int ni = 0; ni < 4; ++ni)
          bf[ni] = *(const short8*)(Bb + (wc * 64 + ni * 16 + l15) * 64 + slot);
#pragma unroll
        for (int mi = 0; mi < 4; ++mi)
#pragma unroll
          for (int ni = 0; ni < 4; ++ni)
            acc[mi][ni] = __builtin_amdgcn_mfma_f32_16x16x32_bf16(af[mi], bf[ni], acc[mi][ni], 0, 0, 0);
      }
      asm volatile("" ::: "memory");
      __builtin_amdgcn_s_barrier();         // all reads of buf[ks&1] done
    }

    // ---- epilogue: single stage; all 4 waves write 128x128 keys, one scan ----
#pragma unroll
    for (int mi = 0; mi < 4; ++mi)
#pragma unroll
      for (int ni = 0; ni < 4; ++ni) {
        const int col = wc * 64 + ni * 16 + l15;
        const float mn = mns[col];
#pragma unroll
        for (int e = 0; e < 4; ++e) {
          const int row = wr * 64 + mi * 16 + lg * 4 + e;
          Kbuf[row * 128 + kswz(row, col)] = mn - 2.0f * acc[mi][ni][e];
        }
      }
    __syncthreads();
    {
      const int row = t >> 1, half = t & 1;
      unsigned tk[TOPC];
#pragma unroll
      for (int s = 0; s < TOPC; ++s) tk[s] = 0xFFFFFFFFu;
#pragma unroll
      for (int q = 0; q < 16; ++q) {
        const int col = half * 64 + q * 4;
        const f32x4 v = *(const f32x4*)(Kbuf + row * 128 + kswz(row, col));
#pragma unroll
        for (int e = 0; e < 4; ++e) {
          const unsigned p = (f2ord(v[e]) & 0xFFFFC000u) | (unsigned)(j0 + col + e);
          if (p < tk[0]) {                  // replace max, bubble down (sorted desc)
            tk[0] = p;
#pragma unroll
            for (int s = 0; s < TOPC - 1; ++s) {
              const unsigned hi = tk[s] > tk[s + 1] ? tk[s] : tk[s + 1];
              const unsigned lo = tk[s] > tk[s + 1] ? tk[s + 1] : tk[s];
              tk[s] = hi; tk[s + 1] = lo;
            }
          }
        }
      }
      const size_t base = (size_t)(r0 + row) * NCAND + (size_t)(pglob * 2 + half) * TOPC;
#pragma unroll
      for (int s = 0; s < TOPC; ++s) cand[base + s] = tk[s];
    }
    __syncthreads();                        // scan done before next-tile staging
  }
}

// ---- merge 1536 packed candidates -> exact-by-key top-16 -> fp64 rerank -> top-9 ----
__global__ void k_rerank(const float* __restrict__ xf, const float* __restrict__ mb,
                         const unsigned int* __restrict__ cand,
                         int* __restrict__ idx9, double* __restrict__ dsv) {
  const int n = blockIdx.x, t = threadIdx.x;
  __shared__ float    xs[DIM];
  __shared__ unsigned cs[NCAND];
  __shared__ unsigned sel[TRR];
  __shared__ double dpart[256];
  __shared__ double d2s[TRR];
  __shared__ double dist_s[TRR];
  __shared__ int    rank_s[TRR];

  const float* xrow = xf + (size_t)n * DIM;
  for (int c = t; c < DIM; c += 256) xs[c] = xrow[c];
  const size_t cb = (size_t)n * NCAND;
  for (int s = t; s < NCAND; s += 256) cs[s] = cand[cb + s];
  __syncthreads();

  if (t < 64) {  // wave 0: 64 lanes x 24 items, 16 extract-min rounds
    unsigned ck[24];
#pragma unroll
    for (int s = 0; s < 24; ++s) ck[s] = cs[t + 64 * s];
    for (int it = 0; it < TRR; ++it) {
      unsigned best = ck[0];
#pragma unroll
      for (int s = 1; s < 24; ++s) best = best < ck[s] ? best : ck[s];
#pragma unroll
      for (int off = 32; off >= 1; off >>= 1) {
        const unsigned o = (unsigned)__shfl_xor((int)best, off);
        best = best < o ? best : o;
      }
      if (t == 0) sel[it] = best;
#pragma unroll
      for (int s = 0; s < 24; ++s) if (ck[s] == best) ck[s] = 0xFFFFFFFFu;
    }
  }
  __syncthreads();
  {
    const int s = t >> 4, l16 = t & 15;
    const int j = (int)(sel[s] & 16383u);
    const float* mrow = mb + (size_t)j * DIM;
    double a = 0.0;
    for (int i = 0; i < 64; ++i) {
      const int c = l16 + (i << 4);
      const double d = (double)xs[c] - (double)mrow[c];
      a += d * d;
    }
    dpart[t] = a;
  }
  __syncthreads();
  if (t < TRR) {
    double v = 0.0;
    for (int i = 0; i < 16; ++i) v += dpart[t * 16 + i];
    d2s[t] = v;
    dist_s[t] = sqrt(v < 1e-12 ? 1e-12 : v);
  }
  __syncthreads();
  if (t < TRR) {
    const double v = d2s[t]; const int id = (int)(sel[t] & 16383u);
    int r = 0;
    for (int u = 0; u < TRR; ++u) {
      const double vu = d2s[u];
      const int idu = (int)(sel[u] & 16383u);
      if (vu < v || (vu == v && idu < id)) ++r;
    }
    rank_s[t] = r;
    if (r < KNN) idx9[n * KNN + r] = id;
  }
  __syncthreads();
  if (t == 0) {
    double sum = 0.0;
    for (int u = 0; u < TRR; ++u) if (rank_s[u] < KNN) sum += dist_s[u];
    dsv[n] = sum * (1.0 / KNN);
  }
}

// ---- global mean/std of per-row mean distance ----
__global__ void k_dsstats(const double* __restrict__ dsv, double* __restrict__ stats) {
  __shared__ double red[1024];
  const int t = threadIdx.x;
  double s = 0.0;
  for (int i = t; i < N_ROWS; i += 1024) s += dsv[i];
  red[t] = s; __syncthreads();
  for (int o = 512; o >= 1; o >>= 1) { if (t < o) red[t] += red[t + o]; __syncthreads(); }
  const double mean = red[0] / (double)N_ROWS;
  __syncthreads();
  double v = 0.0;
  for (int i = t; i < N_ROWS; i += 1024) { const double d = dsv[i] - mean; v += d * d; }
  red[t] = v; __syncthreads();
  for (int o = 512; o >= 1; o >>= 1) { if (t < o) red[t] += red[t + o]; __syncthreads(); }
  if (t == 0) {
    const double fullstd = sqrt(red[0] * (double)DIM / ((double)N_ROWS * DIM - 1.0));
    stats[0] = mean;
    stats[1] = fullstd + 1e-8;
  }
}

// ---- influence, row-norm, sigmoid noise, noised output + maps ----
__global__ void k_final(const float* __restrict__ xf, const float* __restrict__ mb,
                        const float* __restrict__ iw, const float* __restrict__ dwp,
                        const float* __restrict__ eps, const int* __restrict__ idx9,
                        const double* __restrict__ dsv, const double* __restrict__ stats,
                        float* __restrict__ out) {
  const int n = blockIdx.x, t = threadIdx.x;
  __shared__ float xs[DIM];
  __shared__ int js[KNN];
  __shared__ float rs1[4], rs2[4];
  const float* xrow = xf + (size_t)n * DIM;
  for (int c = t; c < DIM; c += 256) xs[c] = xrow[c];
  if (t < KNN) js[t] = idx9[n * KNN + t];
  __syncthreads();

  float infl[4];
  float s1 = 0.f, s2 = 0.f;
#pragma unroll
  for (int q = 0; q < 4; ++q) {
    const int c = t + q * 256;
    const float x = xs[c];
    float a = 0.f;
#pragma unroll
    for (int k = 0; k < KNN; ++k) a += fabsf(x - mb[(size_t)js[k] * DIM + c]);
    const float v = a * (1.0f / KNN) * iw[c];
    infl[q] = v; s1 += v; s2 += v * v;
  }
#pragma unroll
  for (int o = 32; o >= 1; o >>= 1) { s1 += __shfl_down(s1, o); s2 += __shfl_down(s2, o); }
  if ((t & 63) == 0) { rs1[t >> 6] = s1; rs2[t >> 6] = s2; }
  __syncthreads();
  const float sum = rs1[0] + rs1[1] + rs1[2] + rs1[3];
  const float sq  = rs2[0] + rs2[1] + rs2[2] + rs2[3];
  const float mean = sum * (1.0f / DIM);
  float var = (sq - (float)DIM * mean * mean) * (1.0f / (DIM - 1));
  var = fmaxf(var, 0.f);
  const float inv = 1.0f / (sqrtf(var) + 1e-8f);
  const float dn = (float)(((double)dsv[n] - stats[0]) / stats[1]);
  const float zb = dwp[0] * dn;

  const int b = n / 784, hw = n % 784;
  float* op = out + (size_t)b * (1024 * 784) + hw;
  const float* ep = eps + (size_t)n * DIM;
  float si = 0.f, sn = 0.f;
#pragma unroll
  for (int q = 0; q < 4; ++q) {
    const int c = t + q * 256;
    const float v = infl[q];
    const float z = (v - mean) * inv + zb;
    const float ns = 0.01f + 0.49f / (1.0f + expf(-z));
    op[(size_t)c * 784] = xs[c] + ep[c] * ns;
    si += v; sn += ns;
  }
  __syncthreads();  // rs1/rs2 reads above complete before reuse
#pragma unroll
  for (int o = 32; o >= 1; o >>= 1) { si += __shfl_down(si, o); sn += __shfl_down(sn, o); }
  if ((t & 63) == 0) { rs1[t >> 6] = si; rs2[t >> 6] = sn; }
  __syncthreads();
  if (t == 0) {
    out[6422528 + n]        = (rs1[0] + rs1[1] + rs1[2] + rs1[3]) * (1.0f / DIM);
    out[6422528 + 6272 + n] = (rs2[0] + rs2[1] + rs2[2] + rs2[3]) * (1.0f / DIM);
  }
}

extern "C" void kernel_launch(void* const* d_in, const int* in_sizes, int n_in,
                              void* d_out, int out_size, void* d_ws, size_t ws_size,
                              hipStream_t stream) {
  (void)in_sizes; (void)n_in; (void)out_size; (void)ws_size;
  const float* feat = (const float*)d_in[0];
  const float* mb   = (const float*)d_in[1];
  const float* iw   = (const float*)d_in[2];
  const float* dw   = (const float*)d_in[3];
  const float* eps  = (const float*)d_in[4];
  float* out = (float*)d_out;

  char* p = (char*)d_ws;
  float* xf = (float*)p;                     p += (size_t)N_ROWS * DIM * 4;
  unsigned short* xbf = (unsigned short*)p;  p += (size_t)N_ROWS * DIM * 2;
  unsigned short* mbb = (unsigned short*)p;  p += (size_t)M_ROWS * DIM * 2;
  float* mnorm = (float*)p;                  p += (size_t)M_ROWS * 4;
  unsigned int* cand = (unsigned int*)p;     p += (size_t)N_ROWS * NCAND * 4;
  int* idx9 = (int*)p;                       p += (size_t)N_ROWS * KNN * 4;
  p = (char*)(((uintptr_t)p + 255) & ~(uintptr_t)255);
  double* dsv = (double*)p;                  p += (size_t)N_ROWS * 8;
  double* stats = (double*)p;                p += 64;
  // total ~110 MB of d_ws

  k_prep_x<<<N_ROWS, 256, 0, stream>>>(feat, xf, xbf);
  k_prep_m<<<M_ROWS, 256, 0, stream>>>(mb, mbb, mnorm);
  // Two serialized half-B launches keep per-XCD working set under 4 MB L2.
  k_score<<<448, 256, 0, stream>>>(xbf, mbb, mnorm, cand, 0);
  k_score<<<448, 256, 0, stream>>>(xbf, mbb, mnorm, cand, 1);
  k_rerank<<<N_ROWS, 256, 0, stream>>>(xf, mb, cand, idx9, dsv);
  k_dsstats<<<1, 1024, 0, stream>>>(dsv, stats);
  k_final<<<N_ROWS, 256, 0, stream>>>(xf, mb, iw, dw, eps, idx9, dsv, stats, out);
}